// Round 9
// baseline (154.203 us; speedup 1.0000x reference)
//
#include <hip/hip_runtime.h>
#include <hip/hip_bf16.h>
#include <cmath>

#define B_ 8
#define W_LEN_ 1000
#define WP 1024          // W padded; rows >= 1000 are exactly 0 -> lsum pad = +24, subtracted at end
#define E_ 100
#define C_ 50
#define CPAD 64          // A-fragment k-padding (2 x K=32 MFMA steps); c in 50..63 are zeros
#define HP 72            // H row stride (144 B); attn reads bytes 0..127 of each row
#define K_ 3
#define L_ 18000
#define TL 64            // labels per attn block
#define NLBLK ((L_ + TL - 1) / TL)   // 282
#define CWT 16           // w-positions per conv block
#define NSLOT (K_ * (E_ / 4))        // 75 weight slots
#define NWELEM (C_ * E_ * K_)        // 15000 conv_w floats

typedef __attribute__((ext_vector_type(8))) short bf16x8;   // 8 bf16 = 4 VGPRs
typedef __attribute__((ext_vector_type(4))) short bf16x4;   // 4 bf16 = 2 VGPRs
typedef __attribute__((ext_vector_type(4))) float f32x4;

static __device__ __forceinline__ float bf2f(short s) {
    return __uint_as_float(((unsigned)(unsigned short)s) << 16);
}

// ---------------- conv: inline weight transpose->LDS + conv -> bf16 H ----------------
// Weight path: contiguous coalesced fp32 reads of conv_w (L2-hot after block 0),
// cvt bf16, scattered ds_write into wS (cwTs layout). No UO work (attn reads u_w/out_w
// directly now), no prep dispatch. 2 dispatches total.
__global__ __launch_bounds__(256) void conv_kernel(
    const int* __restrict__ x,          // (B, W)
    const float* __restrict__ W_embed,  // (V, E)
    const float* __restrict__ conv_w,   // (C, E, K) fp32
    const float* __restrict__ conv_b,   // (C,)
    __hip_bfloat16* __restrict__ H)     // (B, WP, HP)
{
    __shared__ float4 emb_s[(CWT + 2) * (E_ / 4)];   // 18 rows x 25 f4 = 7.2 KB
    __shared__ bf16x4 wS[NSLOT * C_];                // 75 x 50 x 8B = 30 KB

    const int b  = blockIdx.y;
    const int w0 = blockIdx.x * CWT;
    const int tid = threadIdx.x;

    // ---- weights: contiguous read -> bf16 -> scattered LDS write (slot = k*25 + e/4, elem e%4) ----
    short* wS_s = (short*)wS;
    for (int i = tid; i < NWELEM; i += 256) {          // 59 iters, stride-1 coalesced
        int c = i / (E_ * K_);
        int r = i - c * (E_ * K_);
        int e = r / K_;
        int k = r - e * K_;
        __hip_bfloat16 h = __float2bfloat16(conv_w[i]);
        wS_s[((k * (E_ / 4) + (e >> 2)) * C_ + c) * 4 + (e & 3)] = *reinterpret_cast<short*>(&h);
    }

    for (int i = tid; i < (CWT + 2) * (E_ / 4); i += 256) {
        int row = i / (E_ / 4);
        int e4  = i % (E_ / 4);
        int ws  = w0 - 1 + row;
        float4 v = make_float4(0.f, 0.f, 0.f, 0.f);
        if ((unsigned)ws < (unsigned)W_LEN_)
            v = ((const float4*)(W_embed + (size_t)x[b * W_LEN_ + ws] * E_))[e4];
        emb_s[i] = v;
    }
    __syncthreads();

    const int c  = tid & 63;
    const int wq = tid >> 6;          // 0..3
    const int cc = (c < C_) ? c : 0;  // dead lanes compute c=0, write 0

    f32x4 acc[4];
    const float bias = conv_b[cc];
    #pragma unroll
    for (int j = 0; j < 4; j++) acc[j] = (f32x4){bias, 0.f, 0.f, 0.f};

    const float4* eb = &emb_s[wq * 4 * (E_ / 4)];

    #pragma unroll 5
    for (int i = 0; i < E_ / 4; i++) {
        bf16x4 kb0 = wS[i * C_ + cc];
        bf16x4 kb1 = wS[(25 + i) * C_ + cc];
        bf16x4 kb2 = wS[(50 + i) * C_ + cc];
        float4 k0 = make_float4(bf2f(kb0[0]), bf2f(kb0[1]), bf2f(kb0[2]), bf2f(kb0[3]));
        float4 k1 = make_float4(bf2f(kb1[0]), bf2f(kb1[1]), bf2f(kb1[2]), bf2f(kb1[3]));
        float4 k2 = make_float4(bf2f(kb2[0]), bf2f(kb2[1]), bf2f(kb2[2]), bf2f(kb2[3]));
        float4 e0 = eb[i],       e1 = eb[25 + i],  e2 = eb[50 + i];
        float4 e3 = eb[75 + i],  e4 = eb[100 + i], e5 = eb[125 + i];
        acc[0].x += e0.x*k0.x + e1.x*k1.x + e2.x*k2.x;
        acc[0].y += e0.y*k0.y + e1.y*k1.y + e2.y*k2.y;
        acc[0].z += e0.z*k0.z + e1.z*k1.z + e2.z*k2.z;
        acc[0].w += e0.w*k0.w + e1.w*k1.w + e2.w*k2.w;
        acc[1].x += e1.x*k0.x + e2.x*k1.x + e3.x*k2.x;
        acc[1].y += e1.y*k0.y + e2.y*k1.y + e3.y*k2.y;
        acc[1].z += e1.z*k0.z + e2.z*k1.z + e3.z*k2.z;
        acc[1].w += e1.w*k0.w + e2.w*k1.w + e3.w*k2.w;
        acc[2].x += e2.x*k0.x + e3.x*k1.x + e4.x*k2.x;
        acc[2].y += e2.y*k0.y + e3.y*k1.y + e4.y*k2.y;
        acc[2].z += e2.z*k0.z + e3.z*k1.z + e4.z*k2.z;
        acc[2].w += e2.w*k0.w + e3.w*k1.w + e4.w*k2.w;
        acc[3].x += e3.x*k0.x + e4.x*k1.x + e5.x*k2.x;
        acc[3].y += e3.y*k0.y + e4.y*k1.y + e5.y*k2.y;
        acc[3].z += e3.z*k0.z + e4.z*k1.z + e5.z*k2.z;
        acc[3].w += e3.w*k0.w + e4.w*k1.w + e5.w*k2.w;
    }

    #pragma unroll
    for (int j = 0; j < 4; j++) {
        int w = w0 + wq * 4 + j;
        float v = 0.f;
        if (c < C_ && w < W_LEN_)
            v = tanhf((acc[j].x + acc[j].z) + (acc[j].y + acc[j].w));
        __hip_bfloat16* row = H + ((size_t)b * WP + w) * HP;
        row[c] = __float2bfloat16(v);   // c in 50..63 and w >= 1000 write 0 (padding exactness)
    }
}

// ---------------- attn: direct-from-L2 dual-GEMM + fused softmax-pool ----------------
// Grid (NLBLK, B). 4 waves: (mi,ni); wave tile 32 lbl x 32 w (R5 structure, proven 60.7us).
// A-fragments built DIRECTLY from fp32 u_w/out_w in the prologue with the same
// __float2bfloat16 rounding the old prep pass used -> bit-identical, no UO intermediate
// (saves the prep dispatch + 4.6MB HBM write + ~9MB refetch).
// H is L2-resident: B-frags straight from global (16B loads). Hand double-buffered
// (Ba/Bb); exp via explicit v_mul+v_exp; barrier-free main loop.
__global__ __launch_bounds__(256) void attn_kernel(
    const __hip_bfloat16* __restrict__ H,   // (B, WP, HP)
    const float* __restrict__ u_w,          // (L, C) fp32
    const float* __restrict__ out_w,        // (L, C) fp32
    const float* __restrict__ out_b,        // (L,)
    float* __restrict__ out)                // (B, L)
{
    __shared__ float2 red[2][TL];           // 1 KB

    const int b  = blockIdx.y;
    const int l0 = blockIdx.x * TL;
    const int tid  = threadIdx.x;
    const int lane = tid & 63;
    const int wid  = tid >> 6;
    const int mi = wid & 1, ni = wid >> 1;
    const int col = lane & 15, quad = lane >> 4;

    // loop-invariant A-fragments for U and O, built from fp32 with prep-identical rounding
    bf16x8 Uf[2][2], Of[2][2];
    #pragma unroll
    for (int mt = 0; mt < 2; mt++) {
        int l = l0 + mi * 32 + mt * 16 + col;
        if (l >= L_) l = L_ - 1;                       // clamp; result discarded
        const float* up = u_w   + (size_t)l * C_;
        const float* op = out_w + (size_t)l * C_;
        #pragma unroll
        for (int st = 0; st < 2; st++) {
            bf16x8 uv, ov;
            #pragma unroll
            for (int q = 0; q < 8; q++) {
                int c = st * 32 + quad * 8 + q;
                float uf = (c < C_) ? up[c] : 0.f;
                float of = (c < C_) ? op[c] : 0.f;
                __hip_bfloat16 hu = __float2bfloat16(uf);
                __hip_bfloat16 ho = __float2bfloat16(of);
                uv[q] = *reinterpret_cast<short*>(&hu);
                ov[q] = *reinterpret_cast<short*>(&ho);
            }
            Uf[mt][st] = uv;
            Of[mt][st] = ov;
        }
    }

    f32x4 lsum[2] = {{0.f,0.f,0.f,0.f},{0.f,0.f,0.f,0.f}};
    f32x4 num [2] = {{0.f,0.f,0.f,0.f},{0.f,0.f,0.f,0.f}};
    const f32x4 zero = {0.f, 0.f, 0.f, 0.f};

    // per-lane B-frag base: row = ni*32 + nt*16 + col, byte = quad*16 + st*64 within 144B row
    const char* gB = (const char*)(H + (size_t)b * WP * HP)
                   + ((size_t)(ni * 32 + col) * HP + quad * 8) * 2;

#define WSTEP (64 * HP * 2)   // 9216 B: one 64-w step

#define LOADF(Bf, gp)                                                            \
    {                                                                            \
        const char* _g = (gp);                                                   \
        _Pragma("unroll")                                                        \
        for (int nt = 0; nt < 2; nt++)                                           \
            _Pragma("unroll")                                                    \
            for (int st = 0; st < 2; st++)                                       \
                Bf[nt][st] = *(const bf16x8*)(_g + nt * (16 * HP * 2) + st * 64);\
    }

#define COMPUTE(Bf)                                                              \
    _Pragma("unroll")                                                            \
    for (int nt = 0; nt < 2; nt++) {                                             \
        _Pragma("unroll")                                                        \
        for (int mt = 0; mt < 2; mt++) {                                         \
            __builtin_amdgcn_s_setprio(1);                                       \
            f32x4 S = __builtin_amdgcn_mfma_f32_16x16x32_bf16(Uf[mt][0], Bf[nt][0], zero, 0, 0, 0); \
            S       = __builtin_amdgcn_mfma_f32_16x16x32_bf16(Uf[mt][1], Bf[nt][1], S,    0, 0, 0); \
            f32x4 T = __builtin_amdgcn_mfma_f32_16x16x32_bf16(Of[mt][0], Bf[nt][0], zero, 0, 0, 0); \
            T       = __builtin_amdgcn_mfma_f32_16x16x32_bf16(Of[mt][1], Bf[nt][1], T,    0, 0, 0); \
            __builtin_amdgcn_s_setprio(0);                                       \
            _Pragma("unroll")                                                    \
            for (int r = 0; r < 4; r++) {                                        \
                float p = __builtin_amdgcn_exp2f(S[r] * 1.4426950408889634f);    \
                lsum[mt][r] += p;                                                \
                num [mt][r] += p * T[r];                                         \
            }                                                                    \
        }                                                                        \
    }

    bf16x8 Ba[2][2], Bb[2][2];
    LOADF(Ba, gB)                       // step 0

    #pragma unroll 1
    for (int t = 0; t < WP / 64; t += 2) {
        LOADF(Bb, gB + WSTEP)           // prefetch step t+1 (always valid: 16 steps, even)
        COMPUTE(Ba)                     // step t
        if (t + 2 < WP / 64)
            LOADF(Ba, gB + 2 * WSTEP)   // prefetch step t+2
        COMPUTE(Bb)                     // step t+1
        gB += 2 * WSTEP;
    }

    // reduce the 16 w-cols held per (quad): xor-butterfly on lane bits 0-3
    #pragma unroll
    for (int mt = 0; mt < 2; mt++) {
        #pragma unroll
        for (int r = 0; r < 4; r++) {
            float ls = lsum[mt][r], nm = num[mt][r];
            #pragma unroll
            for (int d = 1; d < 16; d <<= 1) {
                ls += __shfl_xor(ls, d, 64);
                nm += __shfl_xor(nm, d, 64);
            }
            if (col == 0)
                red[ni][mi * 32 + mt * 16 + quad * 4 + r] = make_float2(ls, nm);
        }
    }
    __syncthreads();

    if (tid < TL) {
        int l = l0 + tid;
        if (l < L_) {
            float2 p0 = red[0][tid], p1 = red[1][tid];
            float z = (p0.y + p1.y) / (p0.x + p1.x - (float)(WP - W_LEN_)) + out_b[l];
            out[(size_t)b * L_ + l] = 1.f / (1.f + __expf(-z));
        }
    }
}

extern "C" void kernel_launch(void* const* d_in, const int* in_sizes, int n_in,
                              void* d_out, int out_size, void* d_ws, size_t ws_size,
                              hipStream_t stream) {
    const int*   x       = (const int*)  d_in[0];
    const float* W_embed = (const float*)d_in[1];
    const float* conv_w  = (const float*)d_in[2];
    const float* conv_b  = (const float*)d_in[3];
    const float* u_w     = (const float*)d_in[4];
    const float* out_w   = (const float*)d_in[5];
    const float* out_b   = (const float*)d_in[6];
    float* out = (float*)d_out;

    char* ws = (char*)d_ws;
    __hip_bfloat16* H = (__hip_bfloat16*)ws;   // 8*1024*72*2 = 1,179,648 B

    {
        dim3 grid(WP / CWT, B_);
        conv_kernel<<<grid, 256, 0, stream>>>(x, W_embed, conv_w, conv_b, H);
    }
    {
        dim3 grid(NLBLK, B_);
        attn_kernel<<<grid, 256, 0, stream>>>(H, u_w, out_w, out_b, out);
    }
}

// Round 10
// 148.484 us; speedup vs baseline: 1.0385x; 1.0385x over previous
//
#include <hip/hip_runtime.h>
#include <hip/hip_bf16.h>
#include <cmath>

#define B_ 8
#define W_LEN_ 1000
#define WP 1024          // W padded; rows >= 1000 are exactly 0 -> lsum pad = +24, subtracted at end
#define E_ 100
#define C_ 50
#define CPAD 64          // UO k-padding (2 x K=32 MFMA steps)
#define HP 72            // H row stride (144 B); attn reads bytes 0..127 of each row
#define K_ 3
#define L_ 18000
#define TL 64            // labels per attn block
#define NLBLK ((L_ + TL - 1) / TL)   // 282
#define CWT 16           // w-positions per conv block
#define NSLOT (K_ * (E_ / 4))        // 75 weight slots

typedef __attribute__((ext_vector_type(8))) short bf16x8;   // 8 bf16 = 4 VGPRs
typedef __attribute__((ext_vector_type(4))) short bf16x4;   // 4 bf16 = 2 VGPRs
typedef __attribute__((ext_vector_type(4))) float f32x4;

static __device__ __forceinline__ float bf2f(short s) {
    return __uint_as_float(((unsigned)(unsigned short)s) << 16);
}

// ---------------- prep_all: conv_w -> bf16x4 slots, u_w/out_w -> bf16 (2,L,64) padded ----------------
__global__ __launch_bounds__(256) void prep_all(
    const float* __restrict__ conv_w, const float* __restrict__ u_w,
    const float* __restrict__ out_w,
    bf16x4* __restrict__ cwTs, __hip_bfloat16* __restrict__ UO)
{
    int tid = blockIdx.x * blockDim.x + threadIdx.x;
    if (tid < NSLOT * C_) {
        int slot = tid / C_;
        int c    = tid % C_;
        int k = slot / (E_ / 4);
        int i = slot % (E_ / 4);
        bf16x4 v;
        #pragma unroll
        for (int q = 0; q < 4; q++) {
            __hip_bfloat16 h = __float2bfloat16(conv_w[((size_t)c * E_ + 4 * i + q) * K_ + k]);
            v[q] = *reinterpret_cast<short*>(&h);
        }
        cwTs[tid] = v;
    }
    if (tid < 2 * L_ * CPAD) {
        int c = tid & (CPAD - 1);
        int l = (tid >> 6) % L_;
        int m = tid / (L_ * CPAD);
        const float* src = m ? out_w : u_w;
        float v = (c < C_) ? src[(size_t)l * C_ + c] : 0.f;
        UO[tid] = __float2bfloat16(v);
    }
}

// ---------------- conv: LDS weights (bf16) + LDS embed rows -> bf16 H (B,WP,HP) ----------------
// Block 256 = (c 0..63) x (wq 0..3); thread computes 4 w, weights ds_read_b64 conflict-free.
__global__ __launch_bounds__(256) void conv_kernel(
    const int* __restrict__ x,          // (B, W)
    const float* __restrict__ W_embed,  // (V, E)
    const bf16x4* __restrict__ cwTs,    // (NSLOT, C)
    const float* __restrict__ conv_b,   // (C,)
    __hip_bfloat16* __restrict__ H)     // (B, WP, HP)
{
    __shared__ float4 emb_s[(CWT + 2) * (E_ / 4)];   // 18 rows x 25 f4 = 7.2 KB
    __shared__ bf16x4 wS[NSLOT * C_];                // 75 x 50 x 8B = 30 KB

    const int b  = blockIdx.y;
    const int w0 = blockIdx.x * CWT;
    const int tid = threadIdx.x;

    for (int i = tid; i < NSLOT * C_; i += 256) wS[i] = cwTs[i];

    for (int i = tid; i < (CWT + 2) * (E_ / 4); i += 256) {
        int row = i / (E_ / 4);
        int e4  = i % (E_ / 4);
        int ws  = w0 - 1 + row;
        float4 v = make_float4(0.f, 0.f, 0.f, 0.f);
        if ((unsigned)ws < (unsigned)W_LEN_)
            v = ((const float4*)(W_embed + (size_t)x[b * W_LEN_ + ws] * E_))[e4];
        emb_s[i] = v;
    }
    __syncthreads();

    const int c  = tid & 63;
    const int wq = tid >> 6;          // 0..3
    const int cc = (c < C_) ? c : 0;  // dead lanes compute c=0, write 0

    f32x4 acc[4];
    const float bias = conv_b[cc];
    #pragma unroll
    for (int j = 0; j < 4; j++) acc[j] = (f32x4){bias, 0.f, 0.f, 0.f};

    const float4* eb = &emb_s[wq * 4 * (E_ / 4)];

    #pragma unroll 5
    for (int i = 0; i < E_ / 4; i++) {
        bf16x4 kb0 = wS[i * C_ + cc];
        bf16x4 kb1 = wS[(25 + i) * C_ + cc];
        bf16x4 kb2 = wS[(50 + i) * C_ + cc];
        float4 k0 = make_float4(bf2f(kb0[0]), bf2f(kb0[1]), bf2f(kb0[2]), bf2f(kb0[3]));
        float4 k1 = make_float4(bf2f(kb1[0]), bf2f(kb1[1]), bf2f(kb1[2]), bf2f(kb1[3]));
        float4 k2 = make_float4(bf2f(kb2[0]), bf2f(kb2[1]), bf2f(kb2[2]), bf2f(kb2[3]));
        float4 e0 = eb[i],       e1 = eb[25 + i],  e2 = eb[50 + i];
        float4 e3 = eb[75 + i],  e4 = eb[100 + i], e5 = eb[125 + i];
        acc[0].x += e0.x*k0.x + e1.x*k1.x + e2.x*k2.x;
        acc[0].y += e0.y*k0.y + e1.y*k1.y + e2.y*k2.y;
        acc[0].z += e0.z*k0.z + e1.z*k1.z + e2.z*k2.z;
        acc[0].w += e0.w*k0.w + e1.w*k1.w + e2.w*k2.w;
        acc[1].x += e1.x*k0.x + e2.x*k1.x + e3.x*k2.x;
        acc[1].y += e1.y*k0.y + e2.y*k1.y + e3.y*k2.y;
        acc[1].z += e1.z*k0.z + e2.z*k1.z + e3.z*k2.z;
        acc[1].w += e1.w*k0.w + e2.w*k1.w + e3.w*k2.w;
        acc[2].x += e2.x*k0.x + e3.x*k1.x + e4.x*k2.x;
        acc[2].y += e2.y*k0.y + e3.y*k1.y + e4.y*k2.y;
        acc[2].z += e2.z*k0.z + e3.z*k1.z + e4.z*k2.z;
        acc[2].w += e2.w*k0.w + e3.w*k1.w + e4.w*k2.w;
        acc[3].x += e3.x*k0.x + e4.x*k1.x + e5.x*k2.x;
        acc[3].y += e3.y*k0.y + e4.y*k1.y + e5.y*k2.y;
        acc[3].z += e3.z*k0.z + e4.z*k1.z + e5.z*k2.z;
        acc[3].w += e3.w*k0.w + e4.w*k1.w + e5.w*k2.w;
    }

    #pragma unroll
    for (int j = 0; j < 4; j++) {
        int w = w0 + wq * 4 + j;
        float v = 0.f;
        if (c < C_ && w < W_LEN_)
            v = tanhf((acc[j].x + acc[j].z) + (acc[j].y + acc[j].w));
        __hip_bfloat16* row = H + ((size_t)b * WP + w) * HP;
        row[c] = __float2bfloat16(v);
        if (c < HP - 64) row[64 + c] = __float2bfloat16(0.f);   // zero-fill cols 64..71
    }
}

// ---------------- attn: direct-from-L2 dual-GEMM + fused softmax-pool (R5 + XCD swizzle) ----------------
// Grid (NLBLK, B). 4 waves: (mi,ni); wave tile 32 lbl x 32 w.
// XCD-aware remap (T1): flat=(by*282+bx); g=(flat%8)*282+flat/8 (bijective, 2256=8*282);
// lblk=g/8, b=g%8. Assuming round-robin XCD assignment of dispatch order, each XCD owns a
// contiguous ~36 l-block slice for ALL batches: working set = UO slice (0.58MB) + H (1.18MB)
// < 4MB XCD L2 -> shared operands single-fetch instead of 8-XCD-duplicated thrash
// (R5 FETCH 13.9MB vs ~6MB single-copy ideal; R9's fp32 variant blew it to 26.7MB).
// H L2-resident: B-frags straight from global (16B). Ba/Bb double-buffer; exp2; barrier-free.
__global__ __launch_bounds__(256) void attn_kernel(
    const __hip_bfloat16* __restrict__ H,   // (B, WP, HP)
    const __hip_bfloat16* __restrict__ UO,  // (2, L, CPAD)
    const float* __restrict__ out_b,        // (L,)
    float* __restrict__ out)                // (B, L)
{
    __shared__ float2 red[2][TL];           // 1 KB

    const int flat = blockIdx.y * gridDim.x + blockIdx.x;          // dispatch order, x fastest
    const int g    = (flat & 7) * ((NLBLK * B_) / 8) + (flat >> 3); // bijective XCD chunking
    const int b  = g & 7;
    const int l0 = (g >> 3) * TL;
    const int tid  = threadIdx.x;
    const int lane = tid & 63;
    const int wid  = tid >> 6;
    const int mi = wid & 1, ni = wid >> 1;
    const int col = lane & 15, quad = lane >> 4;

    // loop-invariant A-fragments for U and O
    bf16x8 Uf[2][2], Of[2][2];
    #pragma unroll
    for (int mt = 0; mt < 2; mt++) {
        int l = l0 + mi * 32 + mt * 16 + col;
        if (l >= L_) l = L_ - 1;                       // clamp; result discarded
        const __hip_bfloat16* up = UO + (size_t)l * CPAD + quad * 8;
        const __hip_bfloat16* op = up + (size_t)L_ * CPAD;
        #pragma unroll
        for (int st = 0; st < 2; st++) {
            Uf[mt][st] = *(const bf16x8*)(up + st * 32);
            Of[mt][st] = *(const bf16x8*)(op + st * 32);
        }
    }

    f32x4 lsum[2] = {{0.f,0.f,0.f,0.f},{0.f,0.f,0.f,0.f}};
    f32x4 num [2] = {{0.f,0.f,0.f,0.f},{0.f,0.f,0.f,0.f}};
    const f32x4 zero = {0.f, 0.f, 0.f, 0.f};

    // per-lane B-frag base: row = ni*32 + nt*16 + col, byte = quad*16 + st*64 within 144B row
    const char* gB = (const char*)(H + (size_t)b * WP * HP)
                   + ((size_t)(ni * 32 + col) * HP + quad * 8) * 2;

#define WSTEP (64 * HP * 2)   // 9216 B: one 64-w step

#define LOADF(Bf, gp)                                                            \
    {                                                                            \
        const char* _g = (gp);                                                   \
        _Pragma("unroll")                                                        \
        for (int nt = 0; nt < 2; nt++)                                           \
            _Pragma("unroll")                                                    \
            for (int st = 0; st < 2; st++)                                       \
                Bf[nt][st] = *(const bf16x8*)(_g + nt * (16 * HP * 2) + st * 64);\
    }

#define COMPUTE(Bf)                                                              \
    _Pragma("unroll")                                                            \
    for (int nt = 0; nt < 2; nt++) {                                             \
        _Pragma("unroll")                                                        \
        for (int mt = 0; mt < 2; mt++) {                                         \
            __builtin_amdgcn_s_setprio(1);                                       \
            f32x4 S = __builtin_amdgcn_mfma_f32_16x16x32_bf16(Uf[mt][0], Bf[nt][0], zero, 0, 0, 0); \
            S       = __builtin_amdgcn_mfma_f32_16x16x32_bf16(Uf[mt][1], Bf[nt][1], S,    0, 0, 0); \
            f32x4 T = __builtin_amdgcn_mfma_f32_16x16x32_bf16(Of[mt][0], Bf[nt][0], zero, 0, 0, 0); \
            T       = __builtin_amdgcn_mfma_f32_16x16x32_bf16(Of[mt][1], Bf[nt][1], T,    0, 0, 0); \
            __builtin_amdgcn_s_setprio(0);                                       \
            _Pragma("unroll")                                                    \
            for (int r = 0; r < 4; r++) {                                        \
                float p = __builtin_amdgcn_exp2f(S[r] * 1.4426950408889634f);    \
                lsum[mt][r] += p;                                                \
                num [mt][r] += p * T[r];                                         \
            }                                                                    \
        }                                                                        \
    }

    bf16x8 Ba[2][2], Bb[2][2];
    LOADF(Ba, gB)                       // step 0

    #pragma unroll 1
    for (int t = 0; t < WP / 64; t += 2) {
        LOADF(Bb, gB + WSTEP)           // prefetch step t+1 (always valid: 16 steps, even)
        COMPUTE(Ba)                     // step t
        if (t + 2 < WP / 64)
            LOADF(Ba, gB + 2 * WSTEP)   // prefetch step t+2
        COMPUTE(Bb)                     // step t+1
        gB += 2 * WSTEP;
    }

    // reduce the 16 w-cols held per (quad): xor-butterfly on lane bits 0-3
    #pragma unroll
    for (int mt = 0; mt < 2; mt++) {
        #pragma unroll
        for (int r = 0; r < 4; r++) {
            float ls = lsum[mt][r], nm = num[mt][r];
            #pragma unroll
            for (int d = 1; d < 16; d <<= 1) {
                ls += __shfl_xor(ls, d, 64);
                nm += __shfl_xor(nm, d, 64);
            }
            if (col == 0)
                red[ni][mi * 32 + mt * 16 + quad * 4 + r] = make_float2(ls, nm);
        }
    }
    __syncthreads();

    if (tid < TL) {
        int l = l0 + tid;
        if (l < L_) {
            float2 p0 = red[0][tid], p1 = red[1][tid];
            float z = (p0.y + p1.y) / (p0.x + p1.x - (float)(WP - W_LEN_)) + out_b[l];
            out[(size_t)b * L_ + l] = 1.f / (1.f + __expf(-z));
        }
    }
}

extern "C" void kernel_launch(void* const* d_in, const int* in_sizes, int n_in,
                              void* d_out, int out_size, void* d_ws, size_t ws_size,
                              hipStream_t stream) {
    const int*   x       = (const int*)  d_in[0];
    const float* W_embed = (const float*)d_in[1];
    const float* conv_w  = (const float*)d_in[2];
    const float* conv_b  = (const float*)d_in[3];
    const float* u_w     = (const float*)d_in[4];
    const float* out_w   = (const float*)d_in[5];
    const float* out_b   = (const float*)d_in[6];
    float* out = (float*)d_out;

    char* ws = (char*)d_ws;
    __hip_bfloat16* H  = (__hip_bfloat16*)ws;                 // 8*1024*72*2 = 1,179,648 B
    __hip_bfloat16* UO = (__hip_bfloat16*)(ws + 1179648);     // 2*18000*64*2 = 4,608,000 B
    bf16x4*       cwTs = (bf16x4*)(ws + 1179648 + 4608000);   // 75*50*8 = 30,000 B

    {
        const int total = 2 * L_ * CPAD;   // covers NSLOT*C_ too
        prep_all<<<dim3((total + 255) / 256), 256, 0, stream>>>(conv_w, u_w, out_w, cwTs, UO);
    }
    {
        dim3 grid(WP / CWT, B_);
        conv_kernel<<<grid, 256, 0, stream>>>(x, W_embed, cwTs, conv_b, H);
    }
    {
        dim3 grid(NLBLK, B_);
        attn_kernel<<<grid, 256, 0, stream>>>(H, UO, out_b, out);
    }
}

// Round 11
// 143.877 us; speedup vs baseline: 1.0718x; 1.0320x over previous
//
#include <hip/hip_runtime.h>
#include <hip/hip_bf16.h>
#include <cmath>

#define B_ 8
#define W_LEN_ 1000
#define WP 1024          // W padded; rows >= 1000 are exactly 0 -> lsum pad = +24, subtracted at end
#define E_ 100
#define C_ 50
#define CPAD 64          // UO k-padding (2 x K=32 MFMA steps)
#define HP 72            // H row stride (144 B); attn reads bytes 0..127 of each row
#define K_ 3
#define L_ 18000
#define TL 64            // labels per attn block
#define NLBLK ((L_ + TL - 1) / TL)   // 282
#define CWT 16           // w-positions per conv block
#define NSLOT (K_ * (E_ / 4))        // 75 weight slots
#define NWELEM (C_ * E_ * K_)        // 15000 conv_w floats
#define NCONVBLK 512                 // conv blocks (64 wx x 8 b)
#define NPREPBLK 512                 // UO-prep blocks (grid-strided), same dispatch

typedef __attribute__((ext_vector_type(8))) short bf16x8;   // 8 bf16 = 4 VGPRs
typedef __attribute__((ext_vector_type(4))) short bf16x4;   // 4 bf16 = 2 VGPRs
typedef __attribute__((ext_vector_type(4))) float f32x4;

static __device__ __forceinline__ float bf2f(short s) {
    return __uint_as_float(((unsigned)(unsigned short)s) << 16);
}

// ---------------- conv_prep: block-level fusion of conv and UO prep ----------------
// Blocks 0..511: conv (R8-proven inline weight cvt from contiguous conv_w reads -> LDS;
//                no cwTs global round-trip, no intra-dispatch race).
// Blocks 512..1023: UO prep (u_w/out_w fp32 -> bf16 (2,L,64) zero-padded), grid-strided.
// Concurrent at block granularity -- NOT the R2/R8 thread-level serialization that regressed.
__global__ __launch_bounds__(256) void conv_prep_kernel(
    const int* __restrict__ x,          // (B, W)
    const float* __restrict__ W_embed,  // (V, E)
    const float* __restrict__ conv_w,   // (C, E, K) fp32
    const float* __restrict__ conv_b,   // (C,)
    const float* __restrict__ u_w,      // (L, C) fp32
    const float* __restrict__ out_w,    // (L, C) fp32
    __hip_bfloat16* __restrict__ H,     // (B, WP, HP)
    __hip_bfloat16* __restrict__ UO)    // (2, L, CPAD)
{
    __shared__ float4 emb_s[(CWT + 2) * (E_ / 4)];   // 18 rows x 25 f4 = 7.2 KB
    __shared__ bf16x4 wS[NSLOT * C_];                // 75 x 50 x 8B = 30 KB

    const int gid = blockIdx.x;
    const int tid = threadIdx.x;

    if (gid >= NCONVBLK) {
        // ---- UO prep blocks: coalesced, bit-identical rounding to the old prep pass ----
        const int stride = NPREPBLK * 256;
        for (int idx = (gid - NCONVBLK) * 256 + tid; idx < 2 * L_ * CPAD; idx += stride) {
            int cu = idx & (CPAD - 1);
            int l  = (idx >> 6) % L_;
            int m  = idx / (L_ * CPAD);
            const float* src = m ? out_w : u_w;
            float v = (cu < C_) ? src[(size_t)l * C_ + cu] : 0.f;
            UO[idx] = __float2bfloat16(v);
        }
        return;
    }

    // ---- conv path ----
    const int b  = gid >> 6;            // 0..7
    const int w0 = (gid & 63) * CWT;

    // weights: contiguous coalesced fp32 read -> bf16 -> scattered LDS write (cwTs layout)
    short* wS_s = (short*)wS;
    for (int i = tid; i < NWELEM; i += 256) {          // 59 iters, stride-1 coalesced
        int c = i / (E_ * K_);
        int r = i - c * (E_ * K_);
        int e = r / K_;
        int k = r - e * K_;
        __hip_bfloat16 h = __float2bfloat16(conv_w[i]);
        wS_s[((k * (E_ / 4) + (e >> 2)) * C_ + c) * 4 + (e & 3)] = *reinterpret_cast<short*>(&h);
    }

    for (int i = tid; i < (CWT + 2) * (E_ / 4); i += 256) {
        int row = i / (E_ / 4);
        int e4  = i % (E_ / 4);
        int ws  = w0 - 1 + row;
        float4 v = make_float4(0.f, 0.f, 0.f, 0.f);
        if ((unsigned)ws < (unsigned)W_LEN_)
            v = ((const float4*)(W_embed + (size_t)x[b * W_LEN_ + ws] * E_))[e4];
        emb_s[i] = v;
    }
    __syncthreads();

    const int c  = tid & 63;
    const int wq = tid >> 6;          // 0..3
    const int cc = (c < C_) ? c : 0;  // dead lanes compute c=0, write 0

    f32x4 acc[4];
    const float bias = conv_b[cc];
    #pragma unroll
    for (int j = 0; j < 4; j++) acc[j] = (f32x4){bias, 0.f, 0.f, 0.f};

    const float4* eb = &emb_s[wq * 4 * (E_ / 4)];

    #pragma unroll 5
    for (int i = 0; i < E_ / 4; i++) {
        bf16x4 kb0 = wS[i * C_ + cc];
        bf16x4 kb1 = wS[(25 + i) * C_ + cc];
        bf16x4 kb2 = wS[(50 + i) * C_ + cc];
        float4 k0 = make_float4(bf2f(kb0[0]), bf2f(kb0[1]), bf2f(kb0[2]), bf2f(kb0[3]));
        float4 k1 = make_float4(bf2f(kb1[0]), bf2f(kb1[1]), bf2f(kb1[2]), bf2f(kb1[3]));
        float4 k2 = make_float4(bf2f(kb2[0]), bf2f(kb2[1]), bf2f(kb2[2]), bf2f(kb2[3]));
        float4 e0 = eb[i],       e1 = eb[25 + i],  e2 = eb[50 + i];
        float4 e3 = eb[75 + i],  e4 = eb[100 + i], e5 = eb[125 + i];
        acc[0].x += e0.x*k0.x + e1.x*k1.x + e2.x*k2.x;
        acc[0].y += e0.y*k0.y + e1.y*k1.y + e2.y*k2.y;
        acc[0].z += e0.z*k0.z + e1.z*k1.z + e2.z*k2.z;
        acc[0].w += e0.w*k0.w + e1.w*k1.w + e2.w*k2.w;
        acc[1].x += e1.x*k0.x + e2.x*k1.x + e3.x*k2.x;
        acc[1].y += e1.y*k0.y + e2.y*k1.y + e3.y*k2.y;
        acc[1].z += e1.z*k0.z + e2.z*k1.z + e3.z*k2.z;
        acc[1].w += e1.w*k0.w + e2.w*k1.w + e3.w*k2.w;
        acc[2].x += e2.x*k0.x + e3.x*k1.x + e4.x*k2.x;
        acc[2].y += e2.y*k0.y + e3.y*k1.y + e4.y*k2.y;
        acc[2].z += e2.z*k0.z + e3.z*k1.z + e4.z*k2.z;
        acc[2].w += e2.w*k0.w + e3.w*k1.w + e4.w*k2.w;
        acc[3].x += e3.x*k0.x + e4.x*k1.x + e5.x*k2.x;
        acc[3].y += e3.y*k0.y + e4.y*k1.y + e5.y*k2.y;
        acc[3].z += e3.z*k0.z + e4.z*k1.z + e5.z*k2.z;
        acc[3].w += e3.w*k0.w + e4.w*k1.w + e5.w*k2.w;
    }

    #pragma unroll
    for (int j = 0; j < 4; j++) {
        int w = w0 + wq * 4 + j;
        float v = 0.f;
        if (c < C_ && w < W_LEN_)
            v = tanhf((acc[j].x + acc[j].z) + (acc[j].y + acc[j].w));
        __hip_bfloat16* row = H + ((size_t)b * WP + w) * HP;
        row[c] = __float2bfloat16(v);   // c in 50..63 / w >= 1000 write 0; cols 64..71 never read
    }
}

// ---------------- attn: direct-from-L2 dual-GEMM + fused softmax-pool (R10-exact) ----------------
// Grid (NLBLK, B). 4 waves: (mi,ni); wave tile 32 lbl x 32 w.
// XCD-aware remap (T1): validated -- FETCH 13.9->6.98MB (single-copy ideal); time-neutral
// but strictly less HBM traffic. H L2-resident: B-frags straight from global (16B).
// Ba/Bb double-buffer; exp via v_mul+v_exp; barrier-free main loop.
__global__ __launch_bounds__(256) void attn_kernel(
    const __hip_bfloat16* __restrict__ H,   // (B, WP, HP)
    const __hip_bfloat16* __restrict__ UO,  // (2, L, CPAD)
    const float* __restrict__ out_b,        // (L,)
    float* __restrict__ out)                // (B, L)
{
    __shared__ float2 red[2][TL];           // 1 KB

    const int flat = blockIdx.y * gridDim.x + blockIdx.x;          // dispatch order, x fastest
    const int g    = (flat & 7) * ((NLBLK * B_) / 8) + (flat >> 3); // bijective XCD chunking
    const int b  = g & 7;
    const int l0 = (g >> 3) * TL;
    const int tid  = threadIdx.x;
    const int lane = tid & 63;
    const int wid  = tid >> 6;
    const int mi = wid & 1, ni = wid >> 1;
    const int col = lane & 15, quad = lane >> 4;

    // loop-invariant A-fragments for U and O
    bf16x8 Uf[2][2], Of[2][2];
    #pragma unroll
    for (int mt = 0; mt < 2; mt++) {
        int l = l0 + mi * 32 + mt * 16 + col;
        if (l >= L_) l = L_ - 1;                       // clamp; result discarded
        const __hip_bfloat16* up = UO + (size_t)l * CPAD + quad * 8;
        const __hip_bfloat16* op = up + (size_t)L_ * CPAD;
        #pragma unroll
        for (int st = 0; st < 2; st++) {
            Uf[mt][st] = *(const bf16x8*)(up + st * 32);
            Of[mt][st] = *(const bf16x8*)(op + st * 32);
        }
    }

    f32x4 lsum[2] = {{0.f,0.f,0.f,0.f},{0.f,0.f,0.f,0.f}};
    f32x4 num [2] = {{0.f,0.f,0.f,0.f},{0.f,0.f,0.f,0.f}};
    const f32x4 zero = {0.f, 0.f, 0.f, 0.f};

    // per-lane B-frag base: row = ni*32 + nt*16 + col, byte = quad*16 + st*64 within 144B row
    const char* gB = (const char*)(H + (size_t)b * WP * HP)
                   + ((size_t)(ni * 32 + col) * HP + quad * 8) * 2;

#define WSTEP (64 * HP * 2)   // 9216 B: one 64-w step

#define LOADF(Bf, gp)                                                            \
    {                                                                            \
        const char* _g = (gp);                                                   \
        _Pragma("unroll")                                                        \
        for (int nt = 0; nt < 2; nt++)                                           \
            _Pragma("unroll")                                                    \
            for (int st = 0; st < 2; st++)                                       \
                Bf[nt][st] = *(const bf16x8*)(_g + nt * (16 * HP * 2) + st * 64);\
    }

#define COMPUTE(Bf)                                                              \
    _Pragma("unroll")                                                            \
    for (int nt = 0; nt < 2; nt++) {                                             \
        _Pragma("unroll")                                                        \
        for (int mt = 0; mt < 2; mt++) {                                         \
            __builtin_amdgcn_s_setprio(1);                                       \
            f32x4 S = __builtin_amdgcn_mfma_f32_16x16x32_bf16(Uf[mt][0], Bf[nt][0], zero, 0, 0, 0); \
            S       = __builtin_amdgcn_mfma_f32_16x16x32_bf16(Uf[mt][1], Bf[nt][1], S,    0, 0, 0); \
            f32x4 T = __builtin_amdgcn_mfma_f32_16x16x32_bf16(Of[mt][0], Bf[nt][0], zero, 0, 0, 0); \
            T       = __builtin_amdgcn_mfma_f32_16x16x32_bf16(Of[mt][1], Bf[nt][1], T,    0, 0, 0); \
            __builtin_amdgcn_s_setprio(0);                                       \
            _Pragma("unroll")                                                    \
            for (int r = 0; r < 4; r++) {                                        \
                float p = __builtin_amdgcn_exp2f(S[r] * 1.4426950408889634f);    \
                lsum[mt][r] += p;                                                \
                num [mt][r] += p * T[r];                                         \
            }                                                                    \
        }                                                                        \
    }

    bf16x8 Ba[2][2], Bb[2][2];
    LOADF(Ba, gB)                       // step 0

    #pragma unroll 1
    for (int t = 0; t < WP / 64; t += 2) {
        LOADF(Bb, gB + WSTEP)           // prefetch step t+1 (always valid: 16 steps, even)
        COMPUTE(Ba)                     // step t
        if (t + 2 < WP / 64)
            LOADF(Ba, gB + 2 * WSTEP)   // prefetch step t+2
        COMPUTE(Bb)                     // step t+1
        gB += 2 * WSTEP;
    }

    // reduce the 16 w-cols held per (quad): xor-butterfly on lane bits 0-3
    #pragma unroll
    for (int mt = 0; mt < 2; mt++) {
        #pragma unroll
        for (int r = 0; r < 4; r++) {
            float ls = lsum[mt][r], nm = num[mt][r];
            #pragma unroll
            for (int d = 1; d < 16; d <<= 1) {
                ls += __shfl_xor(ls, d, 64);
                nm += __shfl_xor(nm, d, 64);
            }
            if (col == 0)
                red[ni][mi * 32 + mt * 16 + quad * 4 + r] = make_float2(ls, nm);
        }
    }
    __syncthreads();

    if (tid < TL) {
        int l = l0 + tid;
        if (l < L_) {
            float2 p0 = red[0][tid], p1 = red[1][tid];
            float z = (p0.y + p1.y) / (p0.x + p1.x - (float)(WP - W_LEN_)) + out_b[l];
            out[(size_t)b * L_ + l] = 1.f / (1.f + __expf(-z));
        }
    }
}

extern "C" void kernel_launch(void* const* d_in, const int* in_sizes, int n_in,
                              void* d_out, int out_size, void* d_ws, size_t ws_size,
                              hipStream_t stream) {
    const int*   x       = (const int*)  d_in[0];
    const float* W_embed = (const float*)d_in[1];
    const float* conv_w  = (const float*)d_in[2];
    const float* conv_b  = (const float*)d_in[3];
    const float* u_w     = (const float*)d_in[4];
    const float* out_w   = (const float*)d_in[5];
    const float* out_b   = (const float*)d_in[6];
    float* out = (float*)d_out;

    char* ws = (char*)d_ws;
    __hip_bfloat16* H  = (__hip_bfloat16*)ws;                 // 8*1024*72*2 = 1,179,648 B
    __hip_bfloat16* UO = (__hip_bfloat16*)(ws + 1179648);     // 2*18000*64*2 = 4,608,000 B

    {
        conv_prep_kernel<<<dim3(NCONVBLK + NPREPBLK), 256, 0, stream>>>(
            x, W_embed, conv_w, conv_b, u_w, out_w, H, UO);
    }
    {
        dim3 grid(NLBLK, B_);
        attn_kernel<<<grid, 256, 0, stream>>>(H, UO, out_b, out);
    }
}

// Round 12
// 140.547 us; speedup vs baseline: 1.0972x; 1.0237x over previous
//
#include <hip/hip_runtime.h>
#include <hip/hip_bf16.h>
#include <cmath>

#define B_ 8
#define W_LEN_ 1000
#define WP 1024          // W padded; rows >= 1000 are exactly 0 -> lsum pad = +24, subtracted at end
#define E_ 100
#define C_ 50
#define CPAD 64          // UO k-padding (2 x K=32 MFMA steps)
#define HP 72            // H row stride (144 B); attn reads bytes 0..127 of each row
#define K_ 3
#define L_ 18000
#define TL 64            // labels per attn block
#define NLBLK ((L_ + TL - 1) / TL)   // 282
#define CWT 16           // w-positions per conv block
#define NSLOT (K_ * (E_ / 4))        // 75 weight slots
#define NWELEM (C_ * E_ * K_)        // 15000 conv_w floats
#define NCONVBLK 512                 // conv blocks (64 wx x 8 b)
#define NPREPBLK 512                 // UO-prep blocks (grid-strided), same dispatch

typedef __attribute__((ext_vector_type(8))) short bf16x8;   // 8 bf16 = 4 VGPRs
typedef __attribute__((ext_vector_type(4))) short bf16x4;   // 4 bf16 = 2 VGPRs
typedef __attribute__((ext_vector_type(4))) float f32x4;

static __device__ __forceinline__ float bf2f(short s) {
    return __uint_as_float(((unsigned)(unsigned short)s) << 16);
}

// ---------------- conv_prep: block-level fusion of conv and UO prep (R11-proven) ----------------
__global__ __launch_bounds__(256) void conv_prep_kernel(
    const int* __restrict__ x,          // (B, W)
    const float* __restrict__ W_embed,  // (V, E)
    const float* __restrict__ conv_w,   // (C, E, K) fp32
    const float* __restrict__ conv_b,   // (C,)
    const float* __restrict__ u_w,      // (L, C) fp32
    const float* __restrict__ out_w,    // (L, C) fp32
    __hip_bfloat16* __restrict__ H,     // (B, WP, HP)
    __hip_bfloat16* __restrict__ UO)    // (2, L, CPAD)
{
    __shared__ float4 emb_s[(CWT + 2) * (E_ / 4)];   // 18 rows x 25 f4 = 7.2 KB
    __shared__ bf16x4 wS[NSLOT * C_];                // 75 x 50 x 8B = 30 KB

    const int gid = blockIdx.x;
    const int tid = threadIdx.x;

    if (gid >= NCONVBLK) {
        // ---- UO prep blocks: coalesced, bit-identical rounding to the old prep pass ----
        const int stride = NPREPBLK * 256;
        for (int idx = (gid - NCONVBLK) * 256 + tid; idx < 2 * L_ * CPAD; idx += stride) {
            int cu = idx & (CPAD - 1);
            int l  = (idx >> 6) % L_;
            int m  = idx / (L_ * CPAD);
            const float* src = m ? out_w : u_w;
            float v = (cu < C_) ? src[(size_t)l * C_ + cu] : 0.f;
            UO[idx] = __float2bfloat16(v);
        }
        return;
    }

    // ---- conv path ----
    const int b  = gid >> 6;            // 0..7
    const int w0 = (gid & 63) * CWT;

    // weights: contiguous coalesced fp32 read -> bf16 -> scattered LDS write (cwTs layout)
    short* wS_s = (short*)wS;
    for (int i = tid; i < NWELEM; i += 256) {          // 59 iters, stride-1 coalesced
        int c = i / (E_ * K_);
        int r = i - c * (E_ * K_);
        int e = r / K_;
        int k = r - e * K_;
        __hip_bfloat16 h = __float2bfloat16(conv_w[i]);
        wS_s[((k * (E_ / 4) + (e >> 2)) * C_ + c) * 4 + (e & 3)] = *reinterpret_cast<short*>(&h);
    }

    for (int i = tid; i < (CWT + 2) * (E_ / 4); i += 256) {
        int row = i / (E_ / 4);
        int e4  = i % (E_ / 4);
        int ws  = w0 - 1 + row;
        float4 v = make_float4(0.f, 0.f, 0.f, 0.f);
        if ((unsigned)ws < (unsigned)W_LEN_)
            v = ((const float4*)(W_embed + (size_t)x[b * W_LEN_ + ws] * E_))[e4];
        emb_s[i] = v;
    }
    __syncthreads();

    const int c  = tid & 63;
    const int wq = tid >> 6;          // 0..3
    const int cc = (c < C_) ? c : 0;  // dead lanes compute c=0, write 0

    f32x4 acc[4];
    const float bias = conv_b[cc];
    #pragma unroll
    for (int j = 0; j < 4; j++) acc[j] = (f32x4){bias, 0.f, 0.f, 0.f};

    const float4* eb = &emb_s[wq * 4 * (E_ / 4)];

    #pragma unroll 5
    for (int i = 0; i < E_ / 4; i++) {
        bf16x4 kb0 = wS[i * C_ + cc];
        bf16x4 kb1 = wS[(25 + i) * C_ + cc];
        bf16x4 kb2 = wS[(50 + i) * C_ + cc];
        float4 k0 = make_float4(bf2f(kb0[0]), bf2f(kb0[1]), bf2f(kb0[2]), bf2f(kb0[3]));
        float4 k1 = make_float4(bf2f(kb1[0]), bf2f(kb1[1]), bf2f(kb1[2]), bf2f(kb1[3]));
        float4 k2 = make_float4(bf2f(kb2[0]), bf2f(kb2[1]), bf2f(kb2[2]), bf2f(kb2[3]));
        float4 e0 = eb[i],       e1 = eb[25 + i],  e2 = eb[50 + i];
        float4 e3 = eb[75 + i],  e4 = eb[100 + i], e5 = eb[125 + i];
        acc[0].x += e0.x*k0.x + e1.x*k1.x + e2.x*k2.x;
        acc[0].y += e0.y*k0.y + e1.y*k1.y + e2.y*k2.y;
        acc[0].z += e0.z*k0.z + e1.z*k1.z + e2.z*k2.z;
        acc[0].w += e0.w*k0.w + e1.w*k1.w + e2.w*k2.w;
        acc[1].x += e1.x*k0.x + e2.x*k1.x + e3.x*k2.x;
        acc[1].y += e1.y*k0.y + e2.y*k1.y + e3.y*k2.y;
        acc[1].z += e1.z*k0.z + e2.z*k1.z + e3.z*k2.z;
        acc[1].w += e1.w*k0.w + e2.w*k1.w + e3.w*k2.w;
        acc[2].x += e2.x*k0.x + e3.x*k1.x + e4.x*k2.x;
        acc[2].y += e2.y*k0.y + e3.y*k1.y + e4.y*k2.y;
        acc[2].z += e2.z*k0.z + e3.z*k1.z + e4.z*k2.z;
        acc[2].w += e2.w*k0.w + e3.w*k1.w + e4.w*k2.w;
        acc[3].x += e3.x*k0.x + e4.x*k1.x + e5.x*k2.x;
        acc[3].y += e3.y*k0.y + e4.y*k1.y + e5.y*k2.y;
        acc[3].z += e3.z*k0.z + e4.z*k1.z + e5.z*k2.z;
        acc[3].w += e3.w*k0.w + e4.w*k1.w + e5.w*k2.w;
    }

    #pragma unroll
    for (int j = 0; j < 4; j++) {
        int w = w0 + wq * 4 + j;
        float v = 0.f;
        if (c < C_ && w < W_LEN_)
            v = tanhf((acc[j].x + acc[j].z) + (acc[j].y + acc[j].w));
        __hip_bfloat16* row = H + ((size_t)b * WP + w) * HP;
        row[c] = __float2bfloat16(v);   // c in 50..63 / w >= 1000 write 0; cols 64..71 never read
    }
}

// ---------------- attn: direct-from-L2 dual-GEMM + fused softmax-pool ----------------
// R11 structure + packed-f32 softmax inner: scale/accumulate expressed as f32x4 vector ops
// (compiler emits v_pk_mul/add/fma_f32 pairs; exp stays scalar v_exp). Same ops, same
// order, same f32 arithmetic -> bit-identical output; ~40% fewer VALU issue slots/step.
__global__ __launch_bounds__(256) void attn_kernel(
    const __hip_bfloat16* __restrict__ H,   // (B, WP, HP)
    const __hip_bfloat16* __restrict__ UO,  // (2, L, CPAD)
    const float* __restrict__ out_b,        // (L,)
    float* __restrict__ out)                // (B, L)
{
    __shared__ float2 red[2][TL];           // 1 KB

    const int flat = blockIdx.y * gridDim.x + blockIdx.x;          // dispatch order, x fastest
    const int g    = (flat & 7) * ((NLBLK * B_) / 8) + (flat >> 3); // bijective XCD chunking
    const int b  = g & 7;
    const int l0 = (g >> 3) * TL;
    const int tid  = threadIdx.x;
    const int lane = tid & 63;
    const int wid  = tid >> 6;
    const int mi = wid & 1, ni = wid >> 1;
    const int col = lane & 15, quad = lane >> 4;

    // loop-invariant A-fragments for U and O
    bf16x8 Uf[2][2], Of[2][2];
    #pragma unroll
    for (int mt = 0; mt < 2; mt++) {
        int l = l0 + mi * 32 + mt * 16 + col;
        if (l >= L_) l = L_ - 1;                       // clamp; result discarded
        const __hip_bfloat16* up = UO + (size_t)l * CPAD + quad * 8;
        const __hip_bfloat16* op = up + (size_t)L_ * CPAD;
        #pragma unroll
        for (int st = 0; st < 2; st++) {
            Uf[mt][st] = *(const bf16x8*)(up + st * 32);
            Of[mt][st] = *(const bf16x8*)(op + st * 32);
        }
    }

    f32x4 lsum[2] = {{0.f,0.f,0.f,0.f},{0.f,0.f,0.f,0.f}};
    f32x4 num [2] = {{0.f,0.f,0.f,0.f},{0.f,0.f,0.f,0.f}};
    const f32x4 zero = {0.f, 0.f, 0.f, 0.f};
    const f32x4 vlog2e = {1.4426950408889634f, 1.4426950408889634f,
                          1.4426950408889634f, 1.4426950408889634f};

    // per-lane B-frag base: row = ni*32 + nt*16 + col, byte = quad*16 + st*64 within 144B row
    const char* gB = (const char*)(H + (size_t)b * WP * HP)
                   + ((size_t)(ni * 32 + col) * HP + quad * 8) * 2;

#define WSTEP (64 * HP * 2)   // 9216 B: one 64-w step

#define LOADF(Bf, gp)                                                            \
    {                                                                            \
        const char* _g = (gp);                                                   \
        _Pragma("unroll")                                                        \
        for (int nt = 0; nt < 2; nt++)                                           \
            _Pragma("unroll")                                                    \
            for (int st = 0; st < 2; st++)                                       \
                Bf[nt][st] = *(const bf16x8*)(_g + nt * (16 * HP * 2) + st * 64);\
    }

#define COMPUTE(Bf)                                                              \
    _Pragma("unroll")                                                            \
    for (int nt = 0; nt < 2; nt++) {                                             \
        _Pragma("unroll")                                                        \
        for (int mt = 0; mt < 2; mt++) {                                         \
            __builtin_amdgcn_s_setprio(1);                                       \
            f32x4 S = __builtin_amdgcn_mfma_f32_16x16x32_bf16(Uf[mt][0], Bf[nt][0], zero, 0, 0, 0); \
            S       = __builtin_amdgcn_mfma_f32_16x16x32_bf16(Uf[mt][1], Bf[nt][1], S,    0, 0, 0); \
            f32x4 T = __builtin_amdgcn_mfma_f32_16x16x32_bf16(Of[mt][0], Bf[nt][0], zero, 0, 0, 0); \
            T       = __builtin_amdgcn_mfma_f32_16x16x32_bf16(Of[mt][1], Bf[nt][1], T,    0, 0, 0); \
            __builtin_amdgcn_s_setprio(0);                                       \
            f32x4 Sx = S * vlog2e;            /* packed v_pk_mul_f32 */          \
            f32x4 p;                                                             \
            _Pragma("unroll")                                                    \
            for (int r = 0; r < 4; r++)                                          \
                p[r] = __builtin_amdgcn_exp2f(Sx[r]);                            \
            lsum[mt] = lsum[mt] + p;          /* packed v_pk_add_f32 */          \
            num [mt] = num [mt] + p * T;      /* packed v_pk_fma_f32 */          \
        }                                                                        \
    }

    bf16x8 Ba[2][2], Bb[2][2];
    LOADF(Ba, gB)                       // step 0

    #pragma unroll 1
    for (int t = 0; t < WP / 64; t += 2) {
        LOADF(Bb, gB + WSTEP)           // prefetch step t+1 (always valid: 16 steps, even)
        COMPUTE(Ba)                     // step t
        if (t + 2 < WP / 64)
            LOADF(Ba, gB + 2 * WSTEP)   // prefetch step t+2
        COMPUTE(Bb)                     // step t+1
        gB += 2 * WSTEP;
    }

    // reduce the 16 w-cols held per (quad): xor-butterfly on lane bits 0-3
    #pragma unroll
    for (int mt = 0; mt < 2; mt++) {
        #pragma unroll
        for (int r = 0; r < 4; r++) {
            float ls = lsum[mt][r], nm = num[mt][r];
            #pragma unroll
            for (int d = 1; d < 16; d <<= 1) {
                ls += __shfl_xor(ls, d, 64);
                nm += __shfl_xor(nm, d, 64);
            }
            if (col == 0)
                red[ni][mi * 32 + mt * 16 + quad * 4 + r] = make_float2(ls, nm);
        }
    }
    __syncthreads();

    if (tid < TL) {
        int l = l0 + tid;
        if (l < L_) {
            float2 p0 = red[0][tid], p1 = red[1][tid];
            float z = (p0.y + p1.y) / (p0.x + p1.x - (float)(WP - W_LEN_)) + out_b[l];
            out[(size_t)b * L_ + l] = 1.f / (1.f + __expf(-z));
        }
    }
}

extern "C" void kernel_launch(void* const* d_in, const int* in_sizes, int n_in,
                              void* d_out, int out_size, void* d_ws, size_t ws_size,
                              hipStream_t stream) {
    const int*   x       = (const int*)  d_in[0];
    const float* W_embed = (const float*)d_in[1];
    const float* conv_w  = (const float*)d_in[2];
    const float* conv_b  = (const float*)d_in[3];
    const float* u_w     = (const float*)d_in[4];
    const float* out_w   = (const float*)d_in[5];
    const float* out_b   = (const float*)d_in[6];
    float* out = (float*)d_out;

    char* ws = (char*)d_ws;
    __hip_bfloat16* H  = (__hip_bfloat16*)ws;                 // 8*1024*72*2 = 1,179,648 B
    __hip_bfloat16* UO = (__hip_bfloat16*)(ws + 1179648);     // 2*18000*64*2 = 4,608,000 B

    {
        conv_prep_kernel<<<dim3(NCONVBLK + NPREPBLK), 256, 0, stream>>>(
            x, W_embed, conv_w, conv_b, u_w, out_w, H, UO);
    }
    {
        dim3 grid(NLBLK, B_);
        attn_kernel<<<grid, 256, 0, stream>>>(H, UO, out_b, out);
    }
}